// Round 10
// baseline (130.492 us; speedup 1.0000x reference)
//
#include <hip/hip_runtime.h>

// BNMorph forward — fused per-tile point re-derivation + column-lane splat.
// 64x16 tiles, 128-thread blocks; column-major stride-55 weight table,
// lane = column, 8-row strip per thread -> conflict-free ds_read2_b32 weights.
// B=8, H=320, W=1024. Outputs (concat, f32, each [B,H,W]):
//   0 morphedx, 1 morphedy, 2 orgpts_x, 3 orgpts_y, 4 correspts_x, 5 correspts_y

#define BB 8
#define HH 320
#define WW 1024
#define N_PIX (BB*HH*WW)            // 2,621,440
#define WPI (HH*(WW/32))            // 10240 words per image
#define RR 20
#define TLW 64
#define TLH 16
#define TXN (WW/TLW)                // 16
#define TYN (HH/TLH)                // 20
#define NQ 105
#define CAP 160                     // per-tile candidate capacity (mean ~82)
#define NCR (TLH+40)                // 56 candidate rows
#define NSR (NCR+2)                 // 58 src rows
#define NDR (NCR+6)                 // 62 dst rows
#define NROWT 55                    // table rows: idx i = dyr+7, dyr in [-7,47]
#define NCOLT 46                    // cols 0..44 = dx+20; col 45 = zeros
#define WTABTN 2536                 // 46*55 = 2530, padded to x8
#define WTAB_OFF (2*BB*WPI*4)       // 655360 (16B aligned)

typedef unsigned long long u64;
typedef float v2f __attribute__((ext_vector_type(2)));

// ---- kernel 1: pack maps to bitmasks + build column-major weight table ----
__global__ __launch_bounds__(256) void pack_zero(
    const float* __restrict__ src, const float* __restrict__ dst,
    unsigned* __restrict__ packed, float* __restrict__ wtab_g)
{
    int t = threadIdx.x;
    int i = blockIdx.x * 256 + t;           // float4 index in [0, 2*N_PIX/4)
    if (i < WTABTN) {
        int col = i / NROWT, r = i - col * NROWT;
        int dyr = r - 7;
        float v = 0.0f;
        if (col <= 44 && dyr >= 0 && dyr <= 40) {
            int dxv = col - 20, dyv = dyr - 20;
            float d = sqrtf((float)(dxv * dxv + dyv * dyv));
            v = 0.7f * expf((-d * 1.9f) / 24.0f);
        }
        wtab_g[i] = v;
    }
    const float4* p = (i < (N_PIX >> 2)) ? (const float4*)src + i
                                         : (const float4*)dst + (i - (N_PIX >> 2));
    float4 v = *p;
    unsigned nib = (v.x > 0.5f ? 1u : 0u) | (v.y > 0.5f ? 2u : 0u)
                 | (v.z > 0.5f ? 4u : 0u) | (v.w > 0.5f ? 8u : 0u);
    unsigned val = nib << ((t & 7) * 4);
    val |= __shfl_xor(val, 1);
    val |= __shfl_xor(val, 2);
    val |= __shfl_xor(val, 4);
    if ((t & 7) == 0) packed[i >> 3] = val;
}

// ---- kernel 2: fused point-finding + column-lane splat, 64x16 tiles ----
// 128 threads (2 waves), grid (16, 20, 8) = 2560 blocks, ~16.5 KB LDS.
__global__ __launch_bounds__(128, 4) void fused_morph(
    const unsigned* __restrict__ packed,
    const float* __restrict__ xx, const float* __restrict__ yy,
    const float* __restrict__ wtab_g,
    float* __restrict__ out)
{
    __shared__ __align__(16) float wtabT[WTABTN];    // 9.9 KB, column-major
    __shared__ unsigned sSrc[NSR][6];  // rows ty0-22..ty0+35, pads at word 0,5
    __shared__ unsigned sDst[NDR][6];  // rows ty0-23..ty0+38
    __shared__ __align__(16) unsigned sPt[CAP];
    __shared__ __align__(16) unsigned sWav[2][CAP + 4];  // per-wave filtered lists
    __shared__ int prank[NQ];          // window pos -> (rank<<8)|((dx+7)<<4)|(dy+3)
    __shared__ unsigned char sVB[TLH * TLW];         // in-tile 0x80|vxp7|(vyp3<<4)
    __shared__ int lcnt;

    int t = threadIdx.x;
    int txT = blockIdx.x, tyT = blockIdx.y, b = blockIdx.z;
    int tx0 = txT * TLW, ty0 = tyT * TLH;
    int wb0 = (tx0 >> 5) - 1;
    const unsigned* psrc = packed + (size_t)b * WPI;
    const unsigned* pdst = packed + (size_t)(BB + b) * WPI;

    // stage weight table (634 float4)
    for (int i = t; i < WTABTN / 4; i += 128)
        ((float4*)wtabT)[i] = ((const float4*)wtab_g)[i];
    // stage bitmask halos
    for (int i = t; i < NSR * 4; i += 128) {
        int r = i >> 2, w = (i & 3) + 1;
        int gy = ty0 - 22 + r, gw = wb0 + (w - 1);
        sSrc[r][w] = (gy >= 0 && gy < HH && gw >= 0 && gw < 32) ? psrc[(gy << 5) + gw] : 0u;
    }
    for (int i = t; i < NDR * 4; i += 128) {
        int r = i >> 2, w = (i & 3) + 1;
        int gy = ty0 - 23 + r, gw = wb0 + (w - 1);
        sDst[r][w] = (gy >= 0 && gy < HH && gw >= 0 && gw < 32) ? pdst[(gy << 5) + gw] : 0u;
    }
    if (t < NDR) { sDst[t][0] = 0; sDst[t][5] = 0; if (t < NSR) { sSrc[t][0] = 0; sSrc[t][5] = 0; } }
    if (t < NQ) {
        int dx = (int)xx[t], dy = (int)yy[t];
        prank[(dy + 3) * 15 + (dx + 7)] = (t << 8) | ((dx + 7) << 4) | (dy + 3);
    }
    ((unsigned*)sVB)[t] = 0; ((unsigned*)sVB)[t + 128] = 0;
    if (t == 0) lcnt = 0;
    __syncthreads();

    // Phase A: bit-parallel kept/found over NCR candidate rows x 4 words
    for (int task = t; task < NCR * 4; task += 128) {
        int cr = task >> 2, w = (task & 3) + 1;
        unsigned C = sSrc[cr + 2][w];
        unsigned found = 0;
        if (C) {
            #define EXT5(row) ( (u64)((row)[w-1] >> 30) \
                              | ((u64)(row)[w] << 2) \
                              | ((u64)((row)[w+1] & 3u) << 34) )
            u64 a = EXT5(sSrc[cr]) | EXT5(sSrc[cr + 1]);
            u64 or5 = a | (a >> 1) | (a >> 2) | (a >> 3) | (a >> 4);
            u64 e2 = EXT5(sSrc[cr + 2]);
            unsigned kept = C & ~(unsigned)(or5 | e2 | (e2 >> 1));
            if (kept) {
                u64 dil = 0;
                #pragma unroll
                for (int rr = 0; rr < 7; ++rr) {
                    const unsigned* row = sDst[cr + rr];
                    dil |= (u64)(row[w-1] >> 25) | ((u64)row[w] << 7)
                         | ((u64)(row[w+1] & 0x7Fu) << 39);
                }
                u64 a2 = dil | (dil >> 1);
                u64 b2 = a2 | (a2 >> 2);
                u64 c2 = b2 | (b2 >> 4);
                u64 o15 = c2 | (c2 >> 7);
                found = kept & (unsigned)o15;
            }
        }
        if (w == 1) found &= 0xFFFFF000u;    // px >= tx0-20
        if (w == 4) found &= 0x000FFFFFu;    // px <= tx0+83
        if (found) {
            int nf = __popc(found);
            int base = atomicAdd(&lcnt, nf);
            unsigned fi = found;
            while (fi) {
                int bit = __builtin_ctz(fi); fi &= fi - 1;
                int px = tx0 - 32 + ((w - 1) << 5) + bit;
                if (base < CAP) sPt[base] = (unsigned)((cr << 10) | px);
                ++base;
            }
        }
    }
    __syncthreads();
    int nPts = lcnt; if (nPts > CAP) nPts = CAP;

    // Phase B: per-point nearest-correspondence (minr) + record packing
    for (int i = t; i < nPts; i += 128) {
        unsigned e = sPt[i];
        int cr = (int)(e >> 10), px = (int)(e & 1023u);
        int q = px - tx0 + 25;               // bit (px-7) rel. to LDS word0
        int widx = 1 + (q >> 5), sh = q & 31;
        u64 lo = 0, hi = 0;
        #pragma unroll
        for (int rr = 0; rr < 7; ++rr) {
            const unsigned* row = sDst[cr + rr];
            u64 win = (((u64)row[widx] | ((u64)row[widx + 1] << 32)) >> sh) & 0x7FFFull;
            if (rr < 4) lo |= win << (15 * rr);
            else        hi |= win << (15 * (rr - 4));
        }
        int minv = 0x7FFFFFFF;
        while (lo) { int bb2 = __builtin_ctzll(lo); lo &= lo - 1; int rv = prank[bb2];      if (rv < minv) minv = rv; }
        while (hi) { int bb2 = __builtin_ctzll(hi); hi &= hi - 1; int rv = prank[60 + bb2]; if (rv < minv) minv = rv; }
        int vxp7 = (minv >> 4) & 15, vyp3 = minv & 15;
        int py = ty0 - 20 + cr;
        sPt[i] = (unsigned)px | ((unsigned)py << 10)
               | ((unsigned)vxp7 << 19) | ((unsigned)vyp3 << 23);
        if (px >= tx0 && px < tx0 + TLW && cr >= 20 && cr < 20 + TLH)
            sVB[(cr - 20) * TLW + (px - tx0)] =
                (unsigned char)(0x80 | vxp7 | (vyp3 << 4));
    }
    __syncthreads();

    // Per-wave y-strip compaction (wave-local)
    int lane = t & 63, w = __builtin_amdgcn_readfirstlane(t >> 6);
    int wy0 = ty0 + w * 8;                   // wave strip rows [wy0, wy0+7]
    int cw = 0;
    for (int base = 0; base < nPts; base += 64) {
        int i = base + lane;
        unsigned pk = (i < nPts) ? sPt[i] : 0xFFFFFFFFu;
        int py = (int)((pk >> 10) & 511u);
        bool pass = (i < nPts) & (py >= wy0 - 20) & (py <= wy0 + 27);
        u64 m = __ballot(pass);
        if (pass) {
            int idx = __popcll(m & ((1ull << lane) - 1ull));
            sWav[w][cw + idx] = pk;
        }
        cw += __popcll(m);
    }
    int c4 = (cw + 3) & ~3;
    if (lane < c4 - cw) sWav[w][cw + lane] = 0xFFFFFFFFu;   // sentinel (col-clamps to 45)

    // Phase C: column-lane branchless splat (thread = 1 col x 8 rows)
    int x = tx0 + lane;

    v2f a0p[4] = {};     // row-pair sums: a0p[k] = (Σw row(7-2k), Σw row(6-2k))
    v2f av[8]  = {};     // (a1,a2) per row j

    for (int p = 0; p < c4; p += 4) {
        uint4 P = *(const uint4*)&sWav[w][p];
        #pragma unroll
        for (int k = 0; k < 4; ++k) {
            int spk = __builtin_amdgcn_readfirstlane(
                (int)(k == 0 ? P.x : k == 1 ? P.y : k == 2 ? P.z : P.w));
            int px = spk & 1023;
            int q = ((spk >> 10) & 511) + 20 - wy0;          // scalar, in [0,47] for real pts
            q = q < 0 ? 0 : (q > 47 ? 47 : q);
            float pvx = (float)(((spk >> 19) & 15) - 7);
            float pvy = (float)(((spk >> 23) & 7) - 3);
            v2f vv = {pvx, pvy};

            int col = px + 20 - x;                           // per-lane column
            col = ((unsigned)col > 40u) ? 45 : col;          // zero col for out-of-range
            const float* cb = &wtabT[col * NROWT + q];       // idx q+i = dyr (q-7+i)+7
            float w0 = cb[0], w1 = cb[1], w2 = cb[2], w3 = cb[3];
            float w4 = cb[4], w5 = cb[5], w6 = cb[6], w7 = cb[7];
            // row j (y = wy0+j) uses weight at idx q+7-j
            a0p[0] += (v2f){w0, w1};
            a0p[1] += (v2f){w2, w3};
            a0p[2] += (v2f){w4, w5};
            a0p[3] += (v2f){w6, w7};
            av[7] += w0 * vv;  av[6] += w1 * vv;
            av[5] += w2 * vv;  av[4] += w3 * vv;
            av[3] += w4 * vv;  av[2] += w5 * vv;
            av[1] += w6 * vv;  av[0] += w7 * vv;
        }
    }

    // Epilogue: 8 rows x 6 planes, 64-lane coalesced b32 stores
    size_t bbase = (size_t)b * HH * WW;
    float fx = (float)x;
    #pragma unroll
    for (int j = 0; j < 8; ++j) {
        int y = wy0 + j;
        unsigned vb = sVB[(y - ty0) * TLW + lane];
        float fm  = (float)(vb >> 7);
        float fvx = (float)((int)(vb & 15u) - 7);
        float fvy = (float)((int)((vb >> 4) & 7u) - 3);
        int ai = 7 - j;
        float a0 = (ai & 1) ? a0p[ai >> 1].y : a0p[ai >> 1].x;
        float den = a0 + 1.6f;
        float fy = (float)y;
        size_t idx = bbase + (size_t)y * WW + x;
        out[idx]                   = fx + av[j].x / den;
        out[(size_t)N_PIX + idx]   = fy + av[j].y / den;
        out[2*(size_t)N_PIX + idx] = fx * fm;
        out[3*(size_t)N_PIX + idx] = fy * fm;
        out[4*(size_t)N_PIX + idx] = (fx + fvx) * fm;
        out[5*(size_t)N_PIX + idx] = (fy + fvy) * fm;
    }
}

extern "C" void kernel_launch(void* const* d_in, const int* in_sizes, int n_in,
                              void* d_out, int out_size, void* d_ws, size_t ws_size,
                              hipStream_t stream) {
    const float* src = (const float*)d_in[0];
    const float* dst = (const float*)d_in[1];
    const float* xx  = (const float*)d_in[2];
    const float* yy  = (const float*)d_in[3];
    float* out = (float*)d_out;

    unsigned* packed = (unsigned*)d_ws;
    float*    wtab_g = (float*)((char*)d_ws + WTAB_OFF);

    pack_zero<<<(2 * N_PIX / 4) / 256, 256, 0, stream>>>(src, dst, packed, wtab_g);

    dim3 g2(TXN, TYN, BB);
    fused_morph<<<g2, 128, 0, stream>>>(packed, xx, yy, wtab_g, out);
}

// Round 11
// 124.438 us; speedup vs baseline: 1.0487x; 1.0487x over previous
//
#include <hip/hip_runtime.h>

// BNMorph forward — fused per-tile point re-derivation + wave-compacted splat.
// 64x16 tiles, 128-thread blocks, stride-53 table, interleaved y-groups
// (rows wy0+g, wy0+g+4) so the 4 in-wave y-groups hit disjoint bank classes.
// B=8, H=320, W=1024. Outputs (concat, f32, each [B,H,W]):
//   0 morphedx, 1 morphedy, 2 orgpts_x, 3 orgpts_y, 4 correspts_x, 5 correspts_y

#define BB 8
#define HH 320
#define WW 1024
#define N_PIX (BB*HH*WW)            // 2,621,440
#define WPI (HH*(WW/32))            // 10240 words per image
#define RR 20
#define TLW 64
#define TLH 16
#define TXN (WW/TLW)                // 16
#define TYN (HH/TLH)                // 20
#define NQ 105
#define CAP 160                     // per-tile candidate capacity (mean ~82)
#define NCR (TLH+40)                // 56 candidate rows
#define NSR (NCR+2)                 // 58 src rows
#define NDR (NCR+6)                 // 62 dst rows
#define WSTRIDE 53                  // odd stride
#define WTABN 2228                  // 42*53 = 2226, padded to x4
#define WTAB_OFF (2*BB*WPI*4)       // 655360 (16B aligned)

typedef unsigned long long u64;
typedef float v2f __attribute__((ext_vector_type(2)));

// ---- kernel 1: pack maps to bitmasks + build stride-53 weight table ----
__global__ __launch_bounds__(256) void pack_zero(
    const float* __restrict__ src, const float* __restrict__ dst,
    unsigned* __restrict__ packed, float* __restrict__ wtab_g)
{
    int t = threadIdx.x;
    int i = blockIdx.x * 256 + t;           // float4 index in [0, 2*N_PIX/4)
    if (i < WTABN) {
        int row = i / WSTRIDE, c = i - row * WSTRIDE;
        float v = 0.0f;
        if (row <= 40 && c >= 4 && c <= 44) {
            int dxv = c - 24, dyv = row - 20;
            float d = sqrtf((float)(dxv * dxv + dyv * dyv));
            v = 0.7f * expf((-d * 1.9f) / 24.0f);
        }
        wtab_g[i] = v;
    }
    const float4* p = (i < (N_PIX >> 2)) ? (const float4*)src + i
                                         : (const float4*)dst + (i - (N_PIX >> 2));
    float4 v = *p;
    unsigned nib = (v.x > 0.5f ? 1u : 0u) | (v.y > 0.5f ? 2u : 0u)
                 | (v.z > 0.5f ? 4u : 0u) | (v.w > 0.5f ? 8u : 0u);
    unsigned val = nib << ((t & 7) * 4);
    val |= __shfl_xor(val, 1);
    val |= __shfl_xor(val, 2);
    val |= __shfl_xor(val, 4);
    if ((t & 7) == 0) packed[i >> 3] = val;
}

// ---- kernel 2: fused point-finding + wave-compacted splat, 64x16 tiles ----
// 128 threads (2 waves), grid (16, 20, 8) = 2560 blocks, ~15.2 KB LDS -> 10/CU.
__global__ __launch_bounds__(128, 5) void fused_morph(
    const unsigned* __restrict__ packed,
    const float* __restrict__ xx, const float* __restrict__ yy,
    const float* __restrict__ wtab_g,
    float* __restrict__ out)
{
    __shared__ __align__(16) float wtab[WTABN];      // 8.9 KB
    __shared__ unsigned sSrc[NSR][6];  // rows ty0-22..ty0+35, pads at word 0,5
    __shared__ unsigned sDst[NDR][6];  // rows ty0-23..ty0+38
    __shared__ __align__(16) unsigned sPt[CAP];
    __shared__ __align__(16) unsigned sWav[2][CAP + 4];  // per-wave filtered lists
    __shared__ int prank[NQ];          // window pos -> (rank<<8)|((dx+7)<<4)|(dy+3)
    __shared__ unsigned char sVB[TLH * TLW];         // in-tile 0x80|vxp7|(vyp3<<4)
    __shared__ int lcnt;

    int t = threadIdx.x;
    int txT = blockIdx.x, tyT = blockIdx.y, b = blockIdx.z;
    int tx0 = txT * TLW, ty0 = tyT * TLH;
    int wb0 = (tx0 >> 5) - 1;
    const unsigned* psrc = packed + (size_t)b * WPI;
    const unsigned* pdst = packed + (size_t)(BB + b) * WPI;

    // stage weight table (557 float4)
    for (int i = t; i < WTABN / 4; i += 128)
        ((float4*)wtab)[i] = ((const float4*)wtab_g)[i];
    // stage bitmask halos
    for (int i = t; i < NSR * 4; i += 128) {
        int r = i >> 2, w = (i & 3) + 1;
        int gy = ty0 - 22 + r, gw = wb0 + (w - 1);
        sSrc[r][w] = (gy >= 0 && gy < HH && gw >= 0 && gw < 32) ? psrc[(gy << 5) + gw] : 0u;
    }
    for (int i = t; i < NDR * 4; i += 128) {
        int r = i >> 2, w = (i & 3) + 1;
        int gy = ty0 - 23 + r, gw = wb0 + (w - 1);
        sDst[r][w] = (gy >= 0 && gy < HH && gw >= 0 && gw < 32) ? pdst[(gy << 5) + gw] : 0u;
    }
    if (t < NDR) { sDst[t][0] = 0; sDst[t][5] = 0; if (t < NSR) { sSrc[t][0] = 0; sSrc[t][5] = 0; } }
    if (t < NQ) {
        int dx = (int)xx[t], dy = (int)yy[t];
        prank[(dy + 3) * 15 + (dx + 7)] = (t << 8) | ((dx + 7) << 4) | (dy + 3);
    }
    ((unsigned*)sVB)[t] = 0; ((unsigned*)sVB)[t + 128] = 0;
    if (t == 0) lcnt = 0;
    __syncthreads();

    // Phase A: bit-parallel kept/found over NCR candidate rows x 4 words
    for (int task = t; task < NCR * 4; task += 128) {
        int cr = task >> 2, w = (task & 3) + 1;
        unsigned C = sSrc[cr + 2][w];
        unsigned found = 0;
        if (C) {
            #define EXT5(row) ( (u64)((row)[w-1] >> 30) \
                              | ((u64)(row)[w] << 2) \
                              | ((u64)((row)[w+1] & 3u) << 34) )
            u64 a = EXT5(sSrc[cr]) | EXT5(sSrc[cr + 1]);
            u64 or5 = a | (a >> 1) | (a >> 2) | (a >> 3) | (a >> 4);
            u64 e2 = EXT5(sSrc[cr + 2]);
            unsigned kept = C & ~(unsigned)(or5 | e2 | (e2 >> 1));
            if (kept) {
                u64 dil = 0;
                #pragma unroll
                for (int rr = 0; rr < 7; ++rr) {
                    const unsigned* row = sDst[cr + rr];
                    dil |= (u64)(row[w-1] >> 25) | ((u64)row[w] << 7)
                         | ((u64)(row[w+1] & 0x7Fu) << 39);
                }
                u64 a2 = dil | (dil >> 1);
                u64 b2 = a2 | (a2 >> 2);
                u64 c2 = b2 | (b2 >> 4);
                u64 o15 = c2 | (c2 >> 7);
                found = kept & (unsigned)o15;
            }
        }
        if (w == 1) found &= 0xFFFFF000u;    // px >= tx0-20
        if (w == 4) found &= 0x000FFFFFu;    // px <= tx0+83
        if (found) {
            int nf = __popc(found);
            int base = atomicAdd(&lcnt, nf);
            unsigned fi = found;
            while (fi) {
                int bit = __builtin_ctz(fi); fi &= fi - 1;
                int px = tx0 - 32 + ((w - 1) << 5) + bit;
                if (base < CAP) sPt[base] = (unsigned)((cr << 10) | px);
                ++base;
            }
        }
    }
    __syncthreads();
    int nPts = lcnt; if (nPts > CAP) nPts = CAP;

    // Phase B: per-point nearest-correspondence (minr) + record packing
    for (int i = t; i < nPts; i += 128) {
        unsigned e = sPt[i];
        int cr = (int)(e >> 10), px = (int)(e & 1023u);
        int q = px - tx0 + 25;               // bit (px-7) rel. to LDS word0
        int widx = 1 + (q >> 5), sh = q & 31;
        u64 lo = 0, hi = 0;
        #pragma unroll
        for (int rr = 0; rr < 7; ++rr) {
            const unsigned* row = sDst[cr + rr];
            u64 win = (((u64)row[widx] | ((u64)row[widx + 1] << 32)) >> sh) & 0x7FFFull;
            if (rr < 4) lo |= win << (15 * rr);
            else        hi |= win << (15 * (rr - 4));
        }
        int minv = 0x7FFFFFFF;
        while (lo) { int bb2 = __builtin_ctzll(lo); lo &= lo - 1; int rv = prank[bb2];      if (rv < minv) minv = rv; }
        while (hi) { int bb2 = __builtin_ctzll(hi); hi &= hi - 1; int rv = prank[60 + bb2]; if (rv < minv) minv = rv; }
        int vxp7 = (minv >> 4) & 15, vyp3 = minv & 15;
        int py = ty0 - 20 + cr;
        sPt[i] = (unsigned)px | ((unsigned)py << 10)
               | ((unsigned)vxp7 << 19) | ((unsigned)vyp3 << 23);
        if (px >= tx0 && px < tx0 + TLW && cr >= 20 && cr < 20 + TLH)
            sVB[(cr - 20) * TLW + (px - tx0)] =
                (unsigned char)(0x80 | vxp7 | (vyp3 << 4));
    }
    __syncthreads();

    // Per-wave y-strip compaction (wave-local)
    int lane = t & 63, w = __builtin_amdgcn_readfirstlane(t >> 6);
    int wy0 = ty0 + w * 8;                   // wave strip rows [wy0, wy0+7]
    int cw = 0;
    for (int base = 0; base < nPts; base += 64) {
        int i = base + lane;
        unsigned pk = (i < nPts) ? sPt[i] : 0xFFFFFFFFu;
        int py = (int)((pk >> 10) & 511u);
        bool pass = (i < nPts) & (py >= wy0 - 20) & (py <= wy0 + 27);
        u64 m = __ballot(pass);
        if (pass) {
            int idx = __popcll(m & ((1ull << lane) - 1ull));
            sWav[w][cw + idx] = pk;
        }
        cw += __popcll(m);
    }
    int c4 = (cw + 3) & ~3;
    if (lane < c4 - cw) sWav[w][cw + lane] = 0xFFFFFFFFu;   // py=511 sentinel

    // Phase C: branchless gather-splat. Thread = 4 cols x 2 rows, rows
    // interleaved (wy0+g, wy0+g+4), g = lane>>4  -> y-groups differ by
    // 1 table row = 53 dwords = odd bank shift -> no cross-group aliasing.
    int x0q = tx0 + (lane & 15) * 4;
    int yg  = wy0 + (lane >> 4);             // rows yg, yg+4

    v2f a0p[2][2] = {};          // a0 col-pairs: [ry][0]=(c0,c1) [ry][1]=(c2,c3)
    v2f av[2][4]  = {};          // (a1,a2) per [ry][col]

    for (int p = 0; p < c4; p += 4) {
        uint4 P = *(const uint4*)&sWav[w][p];
        #pragma unroll
        for (int k = 0; k < 4; ++k) {
            int spk = __builtin_amdgcn_readfirstlane(
                (int)(k == 0 ? P.x : k == 1 ? P.y : k == 2 ? P.z : P.w));
            int pxp21 = (spk & 1023) + 21;
            int pyp20 = ((spk >> 10) & 511) + 20;
            float pvx = (float)(((spk >> 19) & 15) - 7);
            float pvy = (float)(((spk >> 23) & 7) - 3);
            v2f vv = {pvx, pvy};

            int coff = pxp21 - x0q;                      // col3's table col
            coff = coff < 0 ? 0 : (coff > 45 ? 45 : coff);
            #pragma unroll
            for (int ry = 0; ry < 2; ++ry) {
                int dyr = pyp20 - (yg + 4 * ry);
                int rowi = ((unsigned)dyr > 40u) ? 41 : dyr;  // row 41 = zeros
                const float* wr = &wtab[rowi * WSTRIDE + coff];
                float w3 = wr[0], w2 = wr[1], w1 = wr[2], w0 = wr[3];
                a0p[ry][0] += (v2f){w0, w1};
                a0p[ry][1] += (v2f){w2, w3};
                av[ry][0] += w0 * vv;
                av[ry][1] += w1 * vv;
                av[ry][2] += w2 * vv;
                av[ry][3] += w3 * vv;
            }
        }
    }

    // Epilogue: all 6 planes, branchless, fully coalesced float4
    size_t bbase = (size_t)b * HH * WW;
    int lx = x0q - tx0;
    #pragma unroll
    for (int ry = 0; ry < 2; ++ry) {
        int y = yg + 4 * ry;
        int ly = y - ty0;
        unsigned vb4 = *(const unsigned*)&sVB[ly * TLW + lx];
        size_t idx = bbase + (size_t)y * WW + x0q;
        float d0 = a0p[ry][0].x + 1.6f, d1 = a0p[ry][0].y + 1.6f;
        float d2 = a0p[ry][1].x + 1.6f, d3 = a0p[ry][1].y + 1.6f;
        float4 ox = { (float)x0q     + av[ry][0].x / d0, (float)(x0q+1) + av[ry][1].x / d1,
                      (float)(x0q+2) + av[ry][2].x / d2, (float)(x0q+3) + av[ry][3].x / d3 };
        float4 oy = { (float)y + av[ry][0].y / d0, (float)y + av[ry][1].y / d1,
                      (float)y + av[ry][2].y / d2, (float)y + av[ry][3].y / d3 };
        float4 o2, o3, o4, o5;
        float* po2 = &o2.x; float* po3 = &o3.x; float* po4 = &o4.x; float* po5 = &o5.x;
        #pragma unroll
        for (int jj = 0; jj < 4; ++jj) {
            unsigned by = (vb4 >> (8 * jj)) & 255u;
            float fm  = (float)(by >> 7);
            float fvx = (float)((int)(by & 15u) - 7);
            float fvy = (float)((int)((by >> 4) & 7u) - 3);
            float fx  = (float)(x0q + jj);
            po2[jj] = fx * fm;
            po3[jj] = (float)y * fm;
            po4[jj] = (fx + fvx) * fm;
            po5[jj] = ((float)y + fvy) * fm;
        }
        *reinterpret_cast<float4*>(out + idx)                     = ox;
        *reinterpret_cast<float4*>(out + (size_t)N_PIX + idx)     = oy;
        *reinterpret_cast<float4*>(out + 2 * (size_t)N_PIX + idx) = o2;
        *reinterpret_cast<float4*>(out + 3 * (size_t)N_PIX + idx) = o3;
        *reinterpret_cast<float4*>(out + 4 * (size_t)N_PIX + idx) = o4;
        *reinterpret_cast<float4*>(out + 5 * (size_t)N_PIX + idx) = o5;
    }
}

extern "C" void kernel_launch(void* const* d_in, const int* in_sizes, int n_in,
                              void* d_out, int out_size, void* d_ws, size_t ws_size,
                              hipStream_t stream) {
    const float* src = (const float*)d_in[0];
    const float* dst = (const float*)d_in[1];
    const float* xx  = (const float*)d_in[2];
    const float* yy  = (const float*)d_in[3];
    float* out = (float*)d_out;

    unsigned* packed = (unsigned*)d_ws;
    float*    wtab_g = (float*)((char*)d_ws + WTAB_OFF);

    pack_zero<<<(2 * N_PIX / 4) / 256, 256, 0, stream>>>(src, dst, packed, wtab_g);

    dim3 g2(TXN, TYN, BB);
    fused_morph<<<g2, 128, 0, stream>>>(packed, xx, yy, wtab_g, out);
}